// Round 4
// baseline (1574.690 us; speedup 1.0000x reference)
//
#include <hip/hip_runtime.h>

// HashEncoder forward: B=1e6 points, D=3, L=16, C=2, H=16, T=2^19.
// Layout: out[b, l*2 + c], i.e. float2 per (b,l) -> out2[b*16 + l].
// Thread = (point, level): tid = b*16 + l. 16M threads total.
//
// Design notes:
//  - Block of 256 threads = 16 points x 16 levels. Input coords (48 floats)
//    staged through LDS by the first 48 lanes (coalesced), then broadcast.
//  - Hashed levels (l>=3) have size exactly 2^19 -> mask, no mod.
//  - Dense levels (l<3) never exceed their table -> no mod at all.
//  - All 8 corner gathers issued before any FMA (one vmcnt window).
//  - Output (128 MB, write-once) stored non-temporally so it doesn't
//    evict the 57 MB embedding table from L2/L3 (hash gathers are
//    L3-served; L3 residency of the table is the performance crux).
//    NOTE: __builtin_nontemporal_store needs a clang ext_vector type,
//    not HIP's float2 class (compile error in R2's kernel).
//  - Expected bound: gather address divergence (~128M distinct-line
//    lane-requests), floor ~208 us at 1 req/cyc/CU.

#define NLEV 16
#define BASE_RES 16
#define HASH_MASK ((1u << 19) - 1u)
#define P1 2654435761u
#define P2 805459861u

typedef float f32x2 __attribute__((ext_vector_type(2)));

__global__ __launch_bounds__(256) void hashenc_kernel(
    const float* __restrict__ inputs,   // [B,3]
    const float* __restrict__ emb,      // [7131219, 2]
    float* __restrict__ out,            // [B, 32]
    int total)                          // B*16
{
    __shared__ float s_in[48];          // 16 points x 3 coords

    const int tloc = threadIdx.x;
    const int tid  = blockIdx.x * 256 + tloc;

    // Stage this block's 16 points (48 floats) coalesced via lanes 0..47.
    if (tloc < 48) {
        s_in[tloc] = inputs[(size_t)(blockIdx.x) * 48 + tloc];
    }
    __syncthreads();

    if (tid >= total) return;

    const int p = tloc >> 4;            // local point 0..15
    const int l = tloc & 15;            // level 0..15

    float vx = s_in[p * 3 + 0];
    float vy = s_in[p * 3 + 1];
    float vz = s_in[p * 3 + 2];

    // normalize to [0,1]: clip((v+1)*0.5, 0, 1)
    vx = fminf(fmaxf((vx + 1.0f) * 0.5f, 0.0f), 1.0f);
    vy = fminf(fmaxf((vy + 1.0f) * 0.5f, 0.0f), 1.0f);
    vz = fminf(fmaxf((vz + 1.0f) * 0.5f, 0.0f), 1.0f);

    const float resf = (float)(BASE_RES << l);

    float px = vx * resf, py = vy * resf, pz = vz * resf;
    // pos >= 0 always, so only the upper clip is needed on floor(pos).
    float gx = fminf(floorf(px), resf - 1.0f);
    float gy = fminf(floorf(py), resf - 1.0f);
    float gz = fminf(floorf(pz), resf - 1.0f);
    float fx = px - gx, fy = py - gy, fz = pz - gz;

    unsigned int cx = (unsigned int)gx;
    unsigned int cy = (unsigned int)gy;
    unsigned int cz = (unsigned int)gz;

    // Per-level base offset into the concatenated table.
    // Dense: 17^3=4913, +33^3=40850, +65^3=315475; hashed: +2^19 each.
    unsigned int off;
    if (l == 0)      off = 0u;
    else if (l == 1) off = 4913u;
    else if (l == 2) off = 40850u;
    else             off = 315475u + (unsigned int)(l - 3) * 524288u;

    // Corner indices. combo bit2 -> dim0(x), bit1 -> dim1(y), bit0 -> dim2(z).
    unsigned int idx[8];
    if (l >= 3) {
        // spatial hash: (x*1) ^ (y*P1) ^ (z*P2), uint32 wraparound, & (2^19-1)
        unsigned int x1  = cx + 1u;
        unsigned int yp0 = cy * P1;
        unsigned int yp1 = yp0 + P1;
        unsigned int zp0 = cz * P2;
        unsigned int zp1 = zp0 + P2;
        idx[0] = (cx ^ yp0 ^ zp0) & HASH_MASK;
        idx[1] = (cx ^ yp0 ^ zp1) & HASH_MASK;
        idx[2] = (cx ^ yp1 ^ zp0) & HASH_MASK;
        idx[3] = (cx ^ yp1 ^ zp1) & HASH_MASK;
        idx[4] = (x1 ^ yp0 ^ zp0) & HASH_MASK;
        idx[5] = (x1 ^ yp0 ^ zp1) & HASH_MASK;
        idx[6] = (x1 ^ yp1 ^ zp0) & HASH_MASK;
        idx[7] = (x1 ^ yp1 ^ zp1) & HASH_MASK;
    } else {
        // dense: x + y*(res+1) + z*(res+1)^2, always < size (no mod needed)
        unsigned int s1 = (unsigned int)resf + 1u;
        unsigned int s2 = s1 * s1;
        unsigned int base = cx + cy * s1 + cz * s2;
        idx[0] = base;
        idx[1] = base + s2;
        idx[2] = base + s1;
        idx[3] = base + s1 + s2;
        idx[4] = base + 1u;
        idx[5] = base + 1u + s2;
        idx[6] = base + 1u + s1;
        idx[7] = base + 1u + s1 + s2;
    }

    // Issue all 8 gathers before consuming (latency batching).
    const f32x2* __restrict__ e2 = (const f32x2*)emb;
    f32x2 f[8];
#pragma unroll
    for (int k = 0; k < 8; ++k) f[k] = e2[off + idx[k]];

    // Trilinear weights: w[k] = wx[bit2] * wy[bit1] * wz[bit0]
    float a0 = 1.0f - fx, a1 = fx;
    float u0 = 1.0f - fy, u1 = fy;
    float txy[4] = {a0 * u0, a0 * u1, a1 * u0, a1 * u1};
    float vv[2]  = {1.0f - fz, fz};

    float acc0 = 0.0f, acc1 = 0.0f;
#pragma unroll
    for (int k = 0; k < 8; ++k) {
        float w = txy[k >> 1] * vv[k & 1];
        acc0 = fmaf(w, f[k].x, acc0);
        acc1 = fmaf(w, f[k].y, acc1);
    }

    // Write-once output: non-temporal, don't pollute L2/L3.
    f32x2 r; r.x = acc0; r.y = acc1;
    __builtin_nontemporal_store(r, (f32x2*)out + tid);
}

extern "C" void kernel_launch(void* const* d_in, const int* in_sizes, int n_in,
                              void* d_out, int out_size, void* d_ws, size_t ws_size,
                              hipStream_t stream) {
    const float* inputs = (const float*)d_in[0];
    const float* emb    = (const float*)d_in[1];
    float* out          = (float*)d_out;

    int B = in_sizes[0] / 3;
    int total = B * NLEV;
    int block = 256;
    int grid = (total + block - 1) / block;
    hashenc_kernel<<<grid, block, 0, stream>>>(inputs, emb, out, total);
}